// Round 18
// baseline (321.568 us; speedup 1.0000x reference)
//
#include <hip/hip_runtime.h>
#include <hip/hip_bf16.h>

typedef __bf16 bf16;
typedef __attribute__((ext_vector_type(4))) __bf16 bf16x4;
typedef __attribute__((ext_vector_type(8))) __bf16 bf16x8;
typedef __attribute__((ext_vector_type(4))) float f32x4;

#define GLD_LDS16(g, l)                                              \
  __builtin_amdgcn_global_load_lds(                                  \
      (const __attribute__((address_space(1))) void*)(g),            \
      (__attribute__((address_space(3))) void*)(l), 16, 0, 0)

// ---- prep: z<3 -> transpose+cast W[z] (K,N)->(N,K) bf16; z==3 -> cast x ----
__global__ void prep_kernel(const float* __restrict__ x,
                            const float* __restrict__ Wq,
                            const float* __restrict__ Wk,
                            const float* __restrict__ Wv,
                            bf16* __restrict__ xb, bf16* __restrict__ Wt) {
  __shared__ float tile[32][33];
  const int z = blockIdx.z;
  const int t = threadIdx.x;
  if (z < 3) {
    const float* W = (z == 0) ? Wq : ((z == 1) ? Wk : Wv);
    bf16* out = Wt + (size_t)z * 1024 * 1024;
    const int k0 = blockIdx.x * 32, n0 = blockIdx.y * 32;
    const int r = t >> 3, c = (t & 7) * 4;
    float4 v = *reinterpret_cast<const float4*>(&W[(size_t)(k0 + r) * 1024 + n0 + c]);
    tile[r][c + 0] = v.x; tile[r][c + 1] = v.y;
    tile[r][c + 2] = v.z; tile[r][c + 3] = v.w;
    __syncthreads();
    bf16x4 o;
    o[0] = (bf16)tile[c + 0][r]; o[1] = (bf16)tile[c + 1][r];
    o[2] = (bf16)tile[c + 2][r]; o[3] = (bf16)tile[c + 3][r];
    *reinterpret_cast<bf16x4*>(&out[(size_t)(n0 + r) * 1024 + k0 + c]) = o;
  } else {
    const int tid = (blockIdx.y * 32 + blockIdx.x) * 256 + t;
#pragma unroll
    for (int i = 0; i < 8; ++i) {
      const int idx = tid + i * 262144;
      float4 v = reinterpret_cast<const float4*>(x)[idx];
      bf16x4 o;
      o[0] = (bf16)v.x; o[1] = (bf16)v.y; o[2] = (bf16)v.z; o[3] = (bf16)v.w;
      reinterpret_cast<bf16x4*>(xb)[idx] = o;
    }
  }
}

// --------- fused QKV GEMM: C[8192][3072] = x @ Wt^T + bias ----------------
// 2-blocks/CU variant: BM=256 BN=192 BK=32, LDS 2x(16K A + 12K B) = 56 KB
// (<=80 KB -> 2 co-resident blocks; prior rounds' 112-147 KB forced 1/CU and
// every barrier stall was a full-CU stall). 8 waves 4Mx2N; 2 phases/tile
// (A-half x full B, 12 MFMA each); 4 DMA/tile; vmcnt(0) boundary (only that
// tile's 4 outstanding; cross-block TLP covers the shallow lead). Granule
// swizzle ^(row>>1)&3 (R9-proven at 32-col rows, 2-way = free).
__global__ __launch_bounds__(512, 4) void qkv_gemm_kernel(
    const bf16* __restrict__ xb, const bf16* __restrict__ Wt,
    const float* __restrict__ bq, const float* __restrict__ bk,
    const float* __restrict__ bv, bf16* __restrict__ QKV) {
  __shared__ bf16 ldsA[2][256 * 32];  // 2 x 16 KB: [buf][half*4096 + row*32 + c]
  __shared__ bf16 ldsB[2][192 * 32];  // 2 x 12 KB: [buf][row*32 + c]

  const int n0g = blockIdx.x * 192;  // may cross q/k/v boundaries
  const int m0 = blockIdx.y * 256;

  const int t = threadIdx.x;
  const int lane = t & 63, wid = t >> 6;
  const int wm = wid >> 1, wn = wid & 1;  // 4M x 2N waves, 64x96 per wave
  const int l15 = lane & 15, kg = lane >> 4;

  // staging: chunk = 128 rows x 32 cols (8 KB); dest row=t>>2, col=(t&3)*8;
  // source col pre-swizzled by ^((row>>1)&3)  [128/64-row offsets are 0 mod 4
  // so chunk-local row phase == absolute row phase]
  const int srow = t >> 2;
  const int scol = ((t & 3) ^ ((t >> 3) & 3)) * 8;

  auto stA = [&](int h, int kt, int wb) {  // half h = rows h*128..+127
    GLD_LDS16(xb + (size_t)(m0 + h * 128 + srow) * 1024 + kt + scol,
              &ldsA[wb][h * 4096 + t * 8]);
  };
  auto stB = [&](int c, int kt, int wb) {  // chunk c rows c*64..c*64+127
    GLD_LDS16(Wt + (size_t)(n0g + c * 64 + srow) * 1024 + kt + scol,
              &ldsB[wb][c * 2048 + t * 8]);
  };
  auto readA = [&](int rb, int ah, int mi) {
    const int row = wm * 32 + mi * 16 + l15;  // 0..127 within half
    const int ce = (kg ^ ((row >> 1) & 3)) * 8;
    return *reinterpret_cast<const bf16x8*>(
        &ldsA[rb][ah * 4096 + row * 32 + ce]);
  };
  auto readB = [&](int rb, int bh, int ni) {
    const int row = bh * 96 + wn * 48 + ni * 16 + l15;  // 0..191
    const int ce = (kg ^ ((row >> 1) & 3)) * 8;
    return *reinterpret_cast<const bf16x8*>(&ldsB[rb][row * 32 + ce]);
  };

  f32x4 acc[2][2][2][3];
#pragma unroll
  for (int a = 0; a < 2; ++a)
#pragma unroll
    for (int b = 0; b < 2; ++b)
#pragma unroll
      for (int i = 0; i < 2; ++i)
#pragma unroll
        for (int j = 0; j < 3; ++j) {
          f32x4 zz = {0.f, 0.f, 0.f, 0.f};
          acc[a][b][i][j] = zz;
        }

  bf16x8 af[2], bfr[2][3];

#define MFMA12(AH)                                                             \
    _Pragma("unroll")                                                          \
    for (int mi = 0; mi < 2; ++mi)                                             \
      _Pragma("unroll")                                                        \
      for (int bh = 0; bh < 2; ++bh)                                           \
        _Pragma("unroll")                                                      \
        for (int ni = 0; ni < 3; ++ni)                                         \
          acc[AH][bh][mi][ni] = __builtin_amdgcn_mfma_f32_16x16x32_bf16(       \
              af[mi], bfr[bh][ni], acc[AH][bh][mi][ni], 0, 0, 0);

// One K-tile: boundary vmcnt(0)+barrier, then P0 (ah=0: 8 reads, stage A of
// tile+1, 12 MFMA) and P1 (ah=1: 2 reads, stage B, 12 MFMA).
#define TILE(RB, WB, KT, DO_STAGE)                                             \
  {                                                                            \
    asm volatile("s_waitcnt vmcnt(0)" ::: "memory");                           \
    __builtin_amdgcn_s_barrier();                                              \
    __builtin_amdgcn_sched_barrier(0);                                         \
    _Pragma("unroll")                                                          \
    for (int mi = 0; mi < 2; ++mi) af[mi] = readA(RB, 0, mi);                  \
    _Pragma("unroll")                                                          \
    for (int bh = 0; bh < 2; ++bh)                                             \
      _Pragma("unroll")                                                        \
      for (int ni = 0; ni < 3; ++ni) bfr[bh][ni] = readB(RB, bh, ni);          \
    __builtin_amdgcn_sched_barrier(0);                                         \
    if (DO_STAGE) { stA(0, (KT) + 32, WB); stA(1, (KT) + 32, WB); }            \
    asm volatile("s_waitcnt lgkmcnt(0)" ::: "memory");                         \
    __builtin_amdgcn_sched_barrier(0);                                         \
    __builtin_amdgcn_s_setprio(1);                                             \
    MFMA12(0)                                                                  \
    __builtin_amdgcn_s_setprio(0);                                             \
    _Pragma("unroll")                                                          \
    for (int mi = 0; mi < 2; ++mi) af[mi] = readA(RB, 1, mi);                  \
    __builtin_amdgcn_sched_barrier(0);                                         \
    if (DO_STAGE) { stB(0, (KT) + 32, WB); stB(1, (KT) + 32, WB); }            \
    asm volatile("s_waitcnt lgkmcnt(0)" ::: "memory");                         \
    __builtin_amdgcn_sched_barrier(0);                                         \
    __builtin_amdgcn_s_setprio(1);                                             \
    MFMA12(1)                                                                  \
    __builtin_amdgcn_s_setprio(0);                                             \
  }

  // prologue: stage tile 0 -> buf0 (4 loads outstanding)
  stA(0, 0, 0); stA(1, 0, 0); stB(0, 0, 0); stB(1, 0, 0);

  // 32 K-tiles in pairs (literal buffer indices); tile 31 stages nothing
  for (int tp = 0; tp < 16; ++tp) {
    const int kb = tp * 64;
    TILE(0, 1, kb, 1)
    TILE(1, 0, kb + 32, tp < 15)
  }
#undef TILE
#undef MFMA12

  // epilogue: C/D layout col = lane&15, row = (lane>>4)*4 + reg  [m89/m91]
  const int rowb = kg * 4;
#pragma unroll
  for (int ah = 0; ah < 2; ++ah)
#pragma unroll
    for (int bh = 0; bh < 2; ++bh)
#pragma unroll
      for (int ni = 0; ni < 3; ++ni) {
        const int col = n0g + bh * 96 + wn * 48 + ni * 16 + l15;
        const int cz = col & 1023;
        const float bv_ =
            (col < 1024) ? bq[cz] : ((col < 2048) ? bk[cz] : bv[cz]);
#pragma unroll
        for (int mi = 0; mi < 2; ++mi) {
          const int row = m0 + ah * 128 + wm * 32 + mi * 16 + rowb;
#pragma unroll
          for (int j = 0; j < 4; ++j)
            QKV[(size_t)(row + j) * 3072 + col] =
                (bf16)(acc[ah][bh][mi][ni][j] + bv_);
        }
      }
}

// ------- local attention, window +-2; 2 positions per wave ----------------
// Transient K-phase then V-phase (low VGPR -> 4 waves/SIMD); Q pre-scaled
// by 1/sqrt(H); bijective XCD-chunk block swizzle for K/V L2 locality.
__global__ __launch_bounds__(256, 4) void local_attn_kernel(
    const bf16* __restrict__ QKV, float* __restrict__ out) {
  const int t = threadIdx.x;
  const int lane = t & 63, wid = t >> 6;
  const int nb = (blockIdx.x & 7) * 128 + (blockIdx.x >> 3);
  const int p0 = nb * 8 + wid * 2;  // even
  const int s0 = p0 & 2047;
  const size_t hoff = (size_t)lane * 16;

  float q0f[16], q1f[16];
  {
    const bf16* qp = QKV + (size_t)p0 * 3072 + hoff;
    bf16x8 a0 = *reinterpret_cast<const bf16x8*>(qp);
    bf16x8 a1 = *reinterpret_cast<const bf16x8*>(qp + 8);
    bf16x8 b0 = *reinterpret_cast<const bf16x8*>(qp + 3072);
    bf16x8 b1 = *reinterpret_cast<const bf16x8*>(qp + 3072 + 8);
#pragma unroll
    for (int j = 0; j < 8; ++j) {
      q0f[j] = (float)a0[j] * (1.0f / 32.0f);
      q0f[8 + j] = (float)a1[j] * (1.0f / 32.0f);
      q1f[j] = (float)b0[j] * (1.0f / 32.0f);
      q1f[8 + j] = (float)b1[j] * (1.0f / 32.0f);
    }
  }

  bool val[6];
#pragma unroll
  for (int r = 0; r < 6; ++r) {
    const int sr = s0 - 2 + r;
    val[r] = (sr >= 0) && (sr < 2048);
  }

  float d0[5], d1[5];
#pragma unroll
  for (int w = 0; w < 5; ++w) { d0[w] = 0.f; d1[w] = 0.f; }
#pragma unroll
  for (int r = 0; r < 6; ++r) {
    if (!val[r]) continue;  // wave-uniform
    const bf16* kp = QKV + (size_t)(p0 - 2 + r) * 3072 + 1024 + hoff;
    bf16x8 k0 = *reinterpret_cast<const bf16x8*>(kp);
    bf16x8 k1 = *reinterpret_cast<const bf16x8*>(kp + 8);
    float kf[16];
#pragma unroll
    for (int j = 0; j < 8; ++j) { kf[j] = (float)k0[j]; kf[8 + j] = (float)k1[j]; }
    if (r < 5) {
      float a = 0.f;
#pragma unroll
      for (int j = 0; j < 16; ++j) a += q0f[j] * kf[j];
      d0[r] = a;
    }
    if (r > 0) {
      float b = 0.f;
#pragma unroll
      for (int j = 0; j < 16; ++j) b += q1f[j] * kf[j];
      d1[r - 1] = b;
    }
  }
#pragma unroll
  for (int off = 32; off >= 1; off >>= 1) {
#pragma unroll
    for (int w = 0; w < 5; ++w) {
      d0[w] += __shfl_xor(d0[w], off, 64);
      d1[w] += __shfl_xor(d1[w], off, 64);
    }
  }

  const float NEG = -__builtin_inff();
  float p0w[5], p1w[5];
  {
    float sc0[5], sc1[5];
#pragma unroll
    for (int w = 0; w < 5; ++w) {
      sc0[w] = val[w] ? d0[w] : NEG;
      sc1[w] = val[w + 1] ? d1[w] : NEG;
    }
    float m0_ = NEG, m1_ = NEG;
#pragma unroll
    for (int w = 0; w < 5; ++w) { m0_ = fmaxf(m0_, sc0[w]); m1_ = fmaxf(m1_, sc1[w]); }
    float su0 = 0.f, su1 = 0.f;
#pragma unroll
    for (int w = 0; w < 5; ++w) {
      p0w[w] = __expf(sc0[w] - m0_); su0 += p0w[w];
      p1w[w] = __expf(sc1[w] - m1_); su1 += p1w[w];
    }
    const float i0 = 1.0f / su0, i1 = 1.0f / su1;
#pragma unroll
    for (int w = 0; w < 5; ++w) { p0w[w] *= i0; p1w[w] *= i1; }
  }

  float of0[16], of1[16];
#pragma unroll
  for (int j = 0; j < 16; ++j) { of0[j] = 0.f; of1[j] = 0.f; }
#pragma unroll
  for (int r = 0; r < 6; ++r) {
    if (!val[r]) continue;
    const bf16* vp = QKV + (size_t)(p0 - 2 + r) * 3072 + 2048 + hoff;
    bf16x8 v0 = *reinterpret_cast<const bf16x8*>(vp);
    bf16x8 v1 = *reinterpret_cast<const bf16x8*>(vp + 8);
    float vf[16];
#pragma unroll
    for (int j = 0; j < 8; ++j) { vf[j] = (float)v0[j]; vf[8 + j] = (float)v1[j]; }
    if (r < 5) {
      const float pw = p0w[r];
#pragma unroll
      for (int j = 0; j < 16; ++j) of0[j] += pw * vf[j];
    }
    if (r > 0) {
      const float pw = p1w[r - 1];
#pragma unroll
      for (int j = 0; j < 16; ++j) of1[j] += pw * vf[j];
    }
  }

  float* op0 = out + (size_t)p0 * 1024 + hoff;
  float* op1 = op0 + 1024;
#pragma unroll
  for (int j4 = 0; j4 < 4; ++j4) {
    f32x4 o0 = {of0[4 * j4], of0[4 * j4 + 1], of0[4 * j4 + 2], of0[4 * j4 + 3]};
    f32x4 o1 = {of1[4 * j4], of1[4 * j4 + 1], of1[4 * j4 + 2], of1[4 * j4 + 3]};
    *reinterpret_cast<f32x4*>(op0 + 4 * j4) = o0;
    *reinterpret_cast<f32x4*>(op1 + 4 * j4) = o1;
  }
}

extern "C" void kernel_launch(void* const* d_in, const int* in_sizes, int n_in,
                              void* d_out, int out_size, void* d_ws,
                              size_t ws_size, hipStream_t stream) {
  const float* x  = (const float*)d_in[0];
  const float* Wq = (const float*)d_in[1];
  const float* bq = (const float*)d_in[2];
  const float* Wk = (const float*)d_in[3];
  const float* bk = (const float*)d_in[4];
  const float* Wv = (const float*)d_in[5];
  const float* bv = (const float*)d_in[6];

  char* ws = (char*)d_ws;
  bf16* xb  = (bf16*)ws;                       // 16 MB: x as bf16
  bf16* Wt  = (bf16*)(ws + (size_t)16777216);  // 6 MB: [3072][1024] W^T bf16
  bf16* QKV = (bf16*)(ws + (size_t)23068672);  // 48 MB: fused [8192][3072]
  float* outf = (float*)d_out;

  prep_kernel<<<dim3(32, 32, 4), 256, 0, stream>>>(x, Wq, Wk, Wv, xb, Wt);
  qkv_gemm_kernel<<<dim3(16, 32), 512, 0, stream>>>(xb, Wt, bq, bk, bv, QKV);
  local_attn_kernel<<<1024, 256, 0, stream>>>(QKV, outf);
}

// Round 19
// 105.465 us; speedup vs baseline: 3.0491x; 3.0491x over previous
//
#include <hip/hip_runtime.h>
#include <hip/hip_bf16.h>

typedef __bf16 bf16;
typedef __attribute__((ext_vector_type(4))) __bf16 bf16x4;
typedef __attribute__((ext_vector_type(8))) __bf16 bf16x8;
typedef __attribute__((ext_vector_type(4))) float f32x4;

#define GLD_LDS16(g, l)                                              \
  __builtin_amdgcn_global_load_lds(                                  \
      (const __attribute__((address_space(1))) void*)(g),            \
      (__attribute__((address_space(3))) void*)(l), 16, 0, 0)

// ---- prep: z<3 -> transpose+cast W[z] (K,N)->(N,K) bf16; z==3 -> cast x ----
__global__ void prep_kernel(const float* __restrict__ x,
                            const float* __restrict__ Wq,
                            const float* __restrict__ Wk,
                            const float* __restrict__ Wv,
                            bf16* __restrict__ xb, bf16* __restrict__ Wt) {
  __shared__ float tile[32][33];
  const int z = blockIdx.z;
  const int t = threadIdx.x;
  if (z < 3) {
    const float* W = (z == 0) ? Wq : ((z == 1) ? Wk : Wv);
    bf16* out = Wt + (size_t)z * 1024 * 1024;
    const int k0 = blockIdx.x * 32, n0 = blockIdx.y * 32;
    const int r = t >> 3, c = (t & 7) * 4;
    float4 v = *reinterpret_cast<const float4*>(&W[(size_t)(k0 + r) * 1024 + n0 + c]);
    tile[r][c + 0] = v.x; tile[r][c + 1] = v.y;
    tile[r][c + 2] = v.z; tile[r][c + 3] = v.w;
    __syncthreads();
    bf16x4 o;
    o[0] = (bf16)tile[c + 0][r]; o[1] = (bf16)tile[c + 1][r];
    o[2] = (bf16)tile[c + 2][r]; o[3] = (bf16)tile[c + 3][r];
    *reinterpret_cast<bf16x4*>(&out[(size_t)(n0 + r) * 1024 + k0 + c]) = o;
  } else {
    const int tid = (blockIdx.y * 32 + blockIdx.x) * 256 + t;
#pragma unroll
    for (int i = 0; i < 8; ++i) {
      const int idx = tid + i * 262144;
      float4 v = reinterpret_cast<const float4*>(x)[idx];
      bf16x4 o;
      o[0] = (bf16)v.x; o[1] = (bf16)v.y; o[2] = (bf16)v.z; o[3] = (bf16)v.w;
      reinterpret_cast<bf16x4*>(xb)[idx] = o;
    }
  }
}

// --------- fused QKV GEMM: C[8192][3072] = x @ Wt^T + bias ----------------
// m97 geometry + R7 schedule: BM=BN=128, BK=32, 4 waves (2Mx2N, 64x64/wave,
// acc 4x4 = 64 AGPR), LDS 3-ring x (8K A + 8K B) = 48 KB -> multi-block/CU
// (m97 precedent ~3 blocks/CU at this class). Counted vmcnt(4) boundaries
// (8 outstanding from tiles t,t+1; retire t's 4), literal ring indices,
// granule swizzle ^((row>>1)&3) (R18-verified at 32-col rows).
// Grid 24x64 = 1536 = exactly 2 rounds at 3/CU. NO launch_bounds min-waves
// (R18's (512,4) cap forced VGPR=64 -> 786 MB scratch spill).
__global__ __launch_bounds__(256) void qkv_gemm_kernel(
    const bf16* __restrict__ xb, const bf16* __restrict__ Wt,
    const float* __restrict__ bq, const float* __restrict__ bk,
    const float* __restrict__ bv, bf16* __restrict__ QKV) {
  __shared__ bf16 ldsA[3][128 * 32];  // 3 x 8 KB
  __shared__ bf16 ldsB[3][128 * 32];  // 3 x 8 KB

  const int n0g = blockIdx.x * 128;  // 128 | 1024 -> never crosses q/k/v
  const int m0 = blockIdx.y * 128;
  const int z = n0g >> 10;
  const float* bias = (z == 0) ? bq : ((z == 1) ? bk : bv);
  const int nloc = n0g & 1023;

  const int t = threadIdx.x;
  const int lane = t & 63, wid = t >> 6;
  const int wr = wid >> 1, wc = wid & 1;  // 2M x 2N waves, 64x64 each
  const int l15 = lane & 15, kg = lane >> 4;

  // staging: chunk = 64 rows x 32 cols (4 KB), 256 thr x 16 B
  // dest: row = t>>2, col = (t&3)*8 ; src col pre-swizzled ^((row>>1)&3)
  const int srow = t >> 2;
  const int scol = ((t & 3) ^ ((t >> 3) & 3)) * 8;

  auto stA = [&](int c, int kt, int wb) {  // chunk c = rows c*64..+63
    GLD_LDS16(xb + (size_t)(m0 + c * 64 + srow) * 1024 + kt + scol,
              &ldsA[wb][c * 2048 + t * 8]);
  };
  auto stB = [&](int c, int kt, int wb) {
    GLD_LDS16(Wt + (size_t)(n0g + c * 64 + srow) * 1024 + kt + scol,
              &ldsB[wb][c * 2048 + t * 8]);
  };
  // fragment reads: BK=32 -> kg covers all 4 granules (full K per MFMA)
  auto readA = [&](int rb, int mi) {
    const int row = wr * 64 + mi * 16 + l15;
    const int ce = (kg ^ ((row >> 1) & 3)) * 8;
    return *reinterpret_cast<const bf16x8*>(&ldsA[rb][row * 32 + ce]);
  };
  auto readB = [&](int rb, int ni) {
    const int row = wc * 64 + ni * 16 + l15;
    const int ce = (kg ^ ((row >> 1) & 3)) * 8;
    return *reinterpret_cast<const bf16x8*>(&ldsB[rb][row * 32 + ce]);
  };

  f32x4 acc[4][4];
#pragma unroll
  for (int i = 0; i < 4; ++i)
#pragma unroll
    for (int j = 0; j < 4; ++j) { f32x4 zz = {0.f, 0.f, 0.f, 0.f}; acc[i][j] = zz; }

  // prologue: tiles 0,1 -> bufs 0,1 (8 DMAs outstanding)
  stA(0, 0, 0); stA(1, 0, 0); stB(0, 0, 0); stB(1, 0, 0);
  stA(0, 32, 1); stA(1, 32, 1); stB(0, 32, 1); stB(1, 32, 1);

// One K-tile (R7 pattern): vmcnt+barrier; 8 frag reads; stage tile+2 (4 DMA);
// 16 MFMA with setprio.
#define KTILE(RB, WB, KT, DO_STAGE, LAST)                                      \
  {                                                                            \
    if (LAST) { asm volatile("s_waitcnt vmcnt(0)" ::: "memory"); }             \
    else      { asm volatile("s_waitcnt vmcnt(4)" ::: "memory"); }             \
    __builtin_amdgcn_s_barrier();                                              \
    bf16x8 af[4], bfr[4];                                                      \
    _Pragma("unroll")                                                          \
    for (int mi = 0; mi < 4; ++mi) af[mi] = readA(RB, mi);                     \
    _Pragma("unroll")                                                          \
    for (int ni = 0; ni < 4; ++ni) bfr[ni] = readB(RB, ni);                    \
    __builtin_amdgcn_sched_barrier(0);                                         \
    if (DO_STAGE) {                                                            \
      stA(0, (KT) + 64, WB); stA(1, (KT) + 64, WB);                            \
      stB(0, (KT) + 64, WB); stB(1, (KT) + 64, WB);                            \
    }                                                                          \
    __builtin_amdgcn_s_setprio(1);                                             \
    _Pragma("unroll")                                                          \
    for (int mi = 0; mi < 4; ++mi)                                             \
      _Pragma("unroll")                                                        \
      for (int ni = 0; ni < 4; ++ni)                                           \
        acc[mi][ni] = __builtin_amdgcn_mfma_f32_16x16x32_bf16(                 \
            af[mi], bfr[ni], acc[mi][ni], 0, 0, 0);                            \
    __builtin_amdgcn_s_setprio(0);                                             \
  }

  // tiles 0..29 in ring-3 groups (stage tile+2); tiles 30,31 tail
  for (int g = 0; g < 10; ++g) {
    const int kb = g * 96;
    KTILE(0, 2, kb,      true, false)
    KTILE(1, 0, kb + 32, true, false)
    KTILE(2, 1, kb + 64, true, false)
  }
  KTILE(0, 2, 960, false, false)  // tile 30
  KTILE(1, 0, 992, false, true)   // tile 31
#undef KTILE

  // epilogue: C/D layout col = lane&15, row = (lane>>4)*4 + reg  [m89/m91]
  const int rowb = kg * 4;
#pragma unroll
  for (int ni = 0; ni < 4; ++ni) {
    const int cl = wc * 64 + ni * 16 + l15;
    const float bv_ = bias[nloc + cl];
#pragma unroll
    for (int mi = 0; mi < 4; ++mi) {
      const int row = m0 + wr * 64 + mi * 16 + rowb;
#pragma unroll
      for (int j = 0; j < 4; ++j)
        QKV[(size_t)(row + j) * 3072 + n0g + cl] = (bf16)(acc[mi][ni][j] + bv_);
    }
  }
}

// ------- local attention, window +-2; 2 positions per wave ----------------
// Transient K-phase then V-phase (low VGPR -> 4 waves/SIMD); Q pre-scaled
// by 1/sqrt(H); bijective XCD-chunk block swizzle for K/V L2 locality.
__global__ __launch_bounds__(256, 4) void local_attn_kernel(
    const bf16* __restrict__ QKV, float* __restrict__ out) {
  const int t = threadIdx.x;
  const int lane = t & 63, wid = t >> 6;
  const int nb = (blockIdx.x & 7) * 128 + (blockIdx.x >> 3);
  const int p0 = nb * 8 + wid * 2;  // even
  const int s0 = p0 & 2047;
  const size_t hoff = (size_t)lane * 16;

  float q0f[16], q1f[16];
  {
    const bf16* qp = QKV + (size_t)p0 * 3072 + hoff;
    bf16x8 a0 = *reinterpret_cast<const bf16x8*>(qp);
    bf16x8 a1 = *reinterpret_cast<const bf16x8*>(qp + 8);
    bf16x8 b0 = *reinterpret_cast<const bf16x8*>(qp + 3072);
    bf16x8 b1 = *reinterpret_cast<const bf16x8*>(qp + 3072 + 8);
#pragma unroll
    for (int j = 0; j < 8; ++j) {
      q0f[j] = (float)a0[j] * (1.0f / 32.0f);
      q0f[8 + j] = (float)a1[j] * (1.0f / 32.0f);
      q1f[j] = (float)b0[j] * (1.0f / 32.0f);
      q1f[8 + j] = (float)b1[j] * (1.0f / 32.0f);
    }
  }

  bool val[6];
#pragma unroll
  for (int r = 0; r < 6; ++r) {
    const int sr = s0 - 2 + r;
    val[r] = (sr >= 0) && (sr < 2048);
  }

  float d0[5], d1[5];
#pragma unroll
  for (int w = 0; w < 5; ++w) { d0[w] = 0.f; d1[w] = 0.f; }
#pragma unroll
  for (int r = 0; r < 6; ++r) {
    if (!val[r]) continue;  // wave-uniform
    const bf16* kp = QKV + (size_t)(p0 - 2 + r) * 3072 + 1024 + hoff;
    bf16x8 k0 = *reinterpret_cast<const bf16x8*>(kp);
    bf16x8 k1 = *reinterpret_cast<const bf16x8*>(kp + 8);
    float kf[16];
#pragma unroll
    for (int j = 0; j < 8; ++j) { kf[j] = (float)k0[j]; kf[8 + j] = (float)k1[j]; }
    if (r < 5) {
      float a = 0.f;
#pragma unroll
      for (int j = 0; j < 16; ++j) a += q0f[j] * kf[j];
      d0[r] = a;
    }
    if (r > 0) {
      float b = 0.f;
#pragma unroll
      for (int j = 0; j < 16; ++j) b += q1f[j] * kf[j];
      d1[r - 1] = b;
    }
  }
#pragma unroll
  for (int off = 32; off >= 1; off >>= 1) {
#pragma unroll
    for (int w = 0; w < 5; ++w) {
      d0[w] += __shfl_xor(d0[w], off, 64);
      d1[w] += __shfl_xor(d1[w], off, 64);
    }
  }

  const float NEG = -__builtin_inff();
  float p0w[5], p1w[5];
  {
    float sc0[5], sc1[5];
#pragma unroll
    for (int w = 0; w < 5; ++w) {
      sc0[w] = val[w] ? d0[w] : NEG;
      sc1[w] = val[w + 1] ? d1[w] : NEG;
    }
    float m0_ = NEG, m1_ = NEG;
#pragma unroll
    for (int w = 0; w < 5; ++w) { m0_ = fmaxf(m0_, sc0[w]); m1_ = fmaxf(m1_, sc1[w]); }
    float su0 = 0.f, su1 = 0.f;
#pragma unroll
    for (int w = 0; w < 5; ++w) {
      p0w[w] = __expf(sc0[w] - m0_); su0 += p0w[w];
      p1w[w] = __expf(sc1[w] - m1_); su1 += p1w[w];
    }
    const float i0 = 1.0f / su0, i1 = 1.0f / su1;
#pragma unroll
    for (int w = 0; w < 5; ++w) { p0w[w] *= i0; p1w[w] *= i1; }
  }

  float of0[16], of1[16];
#pragma unroll
  for (int j = 0; j < 16; ++j) { of0[j] = 0.f; of1[j] = 0.f; }
#pragma unroll
  for (int r = 0; r < 6; ++r) {
    if (!val[r]) continue;
    const bf16* vp = QKV + (size_t)(p0 - 2 + r) * 3072 + 2048 + hoff;
    bf16x8 v0 = *reinterpret_cast<const bf16x8*>(vp);
    bf16x8 v1 = *reinterpret_cast<const bf16x8*>(vp + 8);
    float vf[16];
#pragma unroll
    for (int j = 0; j < 8; ++j) { vf[j] = (float)v0[j]; vf[8 + j] = (float)v1[j]; }
    if (r < 5) {
      const float pw = p0w[r];
#pragma unroll
      for (int j = 0; j < 16; ++j) of0[j] += pw * vf[j];
    }
    if (r > 0) {
      const float pw = p1w[r - 1];
#pragma unroll
      for (int j = 0; j < 16; ++j) of1[j] += pw * vf[j];
    }
  }

  float* op0 = out + (size_t)p0 * 1024 + hoff;
  float* op1 = op0 + 1024;
#pragma unroll
  for (int j4 = 0; j4 < 4; ++j4) {
    f32x4 o0 = {of0[4 * j4], of0[4 * j4 + 1], of0[4 * j4 + 2], of0[4 * j4 + 3]};
    f32x4 o1 = {of1[4 * j4], of1[4 * j4 + 1], of1[4 * j4 + 2], of1[4 * j4 + 3]};
    *reinterpret_cast<f32x4*>(op0 + 4 * j4) = o0;
    *reinterpret_cast<f32x4*>(op1 + 4 * j4) = o1;
  }
}

extern "C" void kernel_launch(void* const* d_in, const int* in_sizes, int n_in,
                              void* d_out, int out_size, void* d_ws,
                              size_t ws_size, hipStream_t stream) {
  const float* x  = (const float*)d_in[0];
  const float* Wq = (const float*)d_in[1];
  const float* bq = (const float*)d_in[2];
  const float* Wk = (const float*)d_in[3];
  const float* bk = (const float*)d_in[4];
  const float* Wv = (const float*)d_in[5];
  const float* bv = (const float*)d_in[6];

  char* ws = (char*)d_ws;
  bf16* xb  = (bf16*)ws;                       // 16 MB: x as bf16
  bf16* Wt  = (bf16*)(ws + (size_t)16777216);  // 6 MB: [3072][1024] W^T bf16
  bf16* QKV = (bf16*)(ws + (size_t)23068672);  // 48 MB: fused [8192][3072]
  float* outf = (float*)d_out;

  prep_kernel<<<dim3(32, 32, 4), 256, 0, stream>>>(x, Wq, Wk, Wv, xb, Wt);
  qkv_gemm_kernel<<<dim3(24, 64), 256, 0, stream>>>(xb, Wt, bq, bk, bv, QKV);
  local_attn_kernel<<<1024, 256, 0, stream>>>(QKV, outf);
}

// Round 20
// 95.101 us; speedup vs baseline: 3.3813x; 1.1090x over previous
//
#include <hip/hip_runtime.h>
#include <hip/hip_bf16.h>

typedef __bf16 bf16;
typedef __attribute__((ext_vector_type(4))) __bf16 bf16x4;
typedef __attribute__((ext_vector_type(8))) __bf16 bf16x8;
typedef __attribute__((ext_vector_type(4))) float f32x4;

#define GLD_LDS16(g, l)                                              \
  __builtin_amdgcn_global_load_lds(                                  \
      (const __attribute__((address_space(1))) void*)(g),            \
      (__attribute__((address_space(3))) void*)(l), 16, 0, 0)

// ---- prep: z<3 -> transpose+cast W[z] (K,N)->(N,K) bf16; z==3 -> cast x ----
__global__ void prep_kernel(const float* __restrict__ x,
                            const float* __restrict__ Wq,
                            const float* __restrict__ Wk,
                            const float* __restrict__ Wv,
                            bf16* __restrict__ xb, bf16* __restrict__ Wt) {
  __shared__ float tile[32][33];
  const int z = blockIdx.z;
  const int t = threadIdx.x;
  if (z < 3) {
    const float* W = (z == 0) ? Wq : ((z == 1) ? Wk : Wv);
    bf16* out = Wt + (size_t)z * 1024 * 1024;
    const int k0 = blockIdx.x * 32, n0 = blockIdx.y * 32;
    const int r = t >> 3, c = (t & 7) * 4;
    float4 v = *reinterpret_cast<const float4*>(&W[(size_t)(k0 + r) * 1024 + n0 + c]);
    tile[r][c + 0] = v.x; tile[r][c + 1] = v.y;
    tile[r][c + 2] = v.z; tile[r][c + 3] = v.w;
    __syncthreads();
    bf16x4 o;
    o[0] = (bf16)tile[c + 0][r]; o[1] = (bf16)tile[c + 1][r];
    o[2] = (bf16)tile[c + 2][r]; o[3] = (bf16)tile[c + 3][r];
    *reinterpret_cast<bf16x4*>(&out[(size_t)(n0 + r) * 1024 + k0 + c]) = o;
  } else {
    const int tid = (blockIdx.y * 32 + blockIdx.x) * 256 + t;
#pragma unroll
    for (int i = 0; i < 8; ++i) {
      const int idx = tid + i * 262144;
      float4 v = reinterpret_cast<const float4*>(x)[idx];
      bf16x4 o;
      o[0] = (bf16)v.x; o[1] = (bf16)v.y; o[2] = (bf16)v.z; o[3] = (bf16)v.w;
      reinterpret_cast<bf16x4*>(xb)[idx] = o;
    }
  }
}

// --------- fused QKV GEMM: C[8192][3072] = x @ Wt^T + bias ----------------
// R15 (best GEMM: 57.5 us): 8-phase, BM=256 BN=192 BK=64, grid 32x16 = 512
// = exactly 2 rounds; 8 waves 4Mx2N; 12 MFMA/phase; vmcnt(4) @P0/P1/P2,
// none @P3; tail 4/2/0. FROZEN (11 structures bracketed; this is optimal).
__global__ __launch_bounds__(512, 2) void qkv_gemm_kernel(
    const bf16* __restrict__ xb, const bf16* __restrict__ Wt,
    const float* __restrict__ bq, const float* __restrict__ bk,
    const float* __restrict__ bv, bf16* __restrict__ QKV) {
  __shared__ bf16 ldsA[2][256 * 64];  // 64 KB
  __shared__ bf16 ldsB[2][192 * 64];  // 48 KB

  const int n0g = blockIdx.x * 192;  // may cross q/k/v boundaries
  const int m0 = blockIdx.y * 256;

  const int t = threadIdx.x;
  const int lane = t & 63, wid = t >> 6;
  const int wm = wid >> 1, wn = wid & 1;
  const int l15 = lane & 15, kg = lane >> 4;

  const int trow = t >> 3;
  const int csrc = (((t & 7) * 16) ^ ((trow & 7) << 4)) >> 1;

  auto stA = [&](int h, int c, int kt, int wb) {
    GLD_LDS16(xb + (size_t)(m0 + h * 128 + c * 64 + trow) * 1024 + kt + csrc,
              &ldsA[wb][h * 8192 + c * 4096 + t * 8]);
  };
  auto stB = [&](int h, int c, int kt, int wb) {
    GLD_LDS16(Wt + (size_t)(n0g + h * 96 + c * 32 + trow) * 1024 + kt + csrc,
              &ldsB[wb][h * 6144 + c * 2048 + t * 8]);
  };
#define STAGE_A(H, KT, WB) { stA(H, 0, KT, WB); stA(H, 1, KT, WB); }
#define STAGE_B(H, KT, WB) { stB(H, 0, KT, WB); stB(H, 1, KT, WB); }

  auto readA = [&](int rb, int ah, int mi, int ks) {
    const int row = wm * 32 + mi * 16 + l15;
    const int colb = (ks * 64 + kg * 16) ^ ((l15 & 7) << 4);
    return *reinterpret_cast<const bf16x8*>(
        &ldsA[rb][ah * 8192 + row * 64 + (colb >> 1)]);
  };
  auto readB = [&](int rb, int bh, int ni, int ks) {
    const int row = wn * 48 + ni * 16 + l15;
    const int colb = (ks * 64 + kg * 16) ^ ((l15 & 7) << 4);
    return *reinterpret_cast<const bf16x8*>(
        &ldsB[rb][bh * 6144 + row * 64 + (colb >> 1)]);
  };

  f32x4 acc[2][2][2][3];
#pragma unroll
  for (int a = 0; a < 2; ++a)
#pragma unroll
    for (int b = 0; b < 2; ++b)
#pragma unroll
      for (int i = 0; i < 2; ++i)
#pragma unroll
        for (int j = 0; j < 3; ++j) {
          f32x4 zz = {0.f, 0.f, 0.f, 0.f};
          acc[a][b][i][j] = zz;
        }

  bf16x8 af[2][2], bf0[3][2], bf1[3][2];

#define MFMA12(AH, BH, BF)                                                     \
    _Pragma("unroll")                                                          \
    for (int mi = 0; mi < 2; ++mi)                                             \
      _Pragma("unroll")                                                        \
      for (int ni = 0; ni < 3; ++ni) {                                         \
        acc[AH][BH][mi][ni] = __builtin_amdgcn_mfma_f32_16x16x32_bf16(         \
            af[mi][0], BF[ni][0], acc[AH][BH][mi][ni], 0, 0, 0);               \
        acc[AH][BH][mi][ni] = __builtin_amdgcn_mfma_f32_16x16x32_bf16(         \
            af[mi][1], BF[ni][1], acc[AH][BH][mi][ni], 0, 0, 0);               \
      }

#define PHASE0(RB, WB, KST, DO_STAGE, WN)                                      \
  {                                                                            \
    asm volatile("s_waitcnt vmcnt(" #WN ")" ::: "memory");                     \
    __builtin_amdgcn_s_barrier();                                              \
    __builtin_amdgcn_sched_barrier(0);                                         \
    _Pragma("unroll")                                                          \
    for (int mi = 0; mi < 2; ++mi)                                             \
      _Pragma("unroll")                                                        \
      for (int ks = 0; ks < 2; ++ks) af[mi][ks] = readA(RB, 0, mi, ks);        \
    _Pragma("unroll")                                                          \
    for (int ni = 0; ni < 3; ++ni)                                             \
      _Pragma("unroll")                                                        \
      for (int ks = 0; ks < 2; ++ks) bf0[ni][ks] = readB(RB, 0, ni, ks);       \
    __builtin_amdgcn_sched_barrier(0);                                         \
    if (DO_STAGE) STAGE_A(0, KST, WB);                                         \
    asm volatile("s_waitcnt lgkmcnt(0)" ::: "memory");                         \
    __builtin_amdgcn_sched_barrier(0);                                         \
    __builtin_amdgcn_s_setprio(1);                                             \
    MFMA12(0, 0, bf0)                                                          \
    __builtin_amdgcn_s_setprio(0);                                             \
  }

#define PHASE1(RB, WB, KST, DO_STAGE, WN)                                      \
  {                                                                            \
    asm volatile("s_waitcnt vmcnt(" #WN ")" ::: "memory");                     \
    __builtin_amdgcn_s_barrier();                                              \
    __builtin_amdgcn_sched_barrier(0);                                         \
    _Pragma("unroll")                                                          \
    for (int ni = 0; ni < 3; ++ni)                                             \
      _Pragma("unroll")                                                        \
      for (int ks = 0; ks < 2; ++ks) bf1[ni][ks] = readB(RB, 1, ni, ks);       \
    __builtin_amdgcn_sched_barrier(0);                                         \
    if (DO_STAGE) STAGE_B(0, KST, WB);                                         \
    asm volatile("s_waitcnt lgkmcnt(0)" ::: "memory");                         \
    __builtin_amdgcn_sched_barrier(0);                                         \
    __builtin_amdgcn_s_setprio(1);                                             \
    MFMA12(0, 1, bf1)                                                          \
    __builtin_amdgcn_s_setprio(0);                                             \
  }

#define PHASE2(RB, WB, KST, DO_STAGE, WN)                                      \
  {                                                                            \
    asm volatile("s_waitcnt vmcnt(" #WN ")" ::: "memory");                     \
    __builtin_amdgcn_s_barrier();                                              \
    __builtin_amdgcn_sched_barrier(0);                                         \
    _Pragma("unroll")                                                          \
    for (int mi = 0; mi < 2; ++mi)                                             \
      _Pragma("unroll")                                                        \
      for (int ks = 0; ks < 2; ++ks) af[mi][ks] = readA(RB, 1, mi, ks);        \
    __builtin_amdgcn_sched_barrier(0);                                         \
    if (DO_STAGE) STAGE_B(1, KST, WB);                                         \
    asm volatile("s_waitcnt lgkmcnt(0)" ::: "memory");                         \
    __builtin_amdgcn_sched_barrier(0);                                         \
    __builtin_amdgcn_s_setprio(1);                                             \
    MFMA12(1, 1, bf1)                                                          \
    __builtin_amdgcn_s_setprio(0);                                             \
  }

#define PHASE3(RB, WB, KST, DO_STAGE)                                          \
  {                                                                            \
    if (DO_STAGE) STAGE_A(1, KST, WB);                                         \
    __builtin_amdgcn_s_setprio(1);                                             \
    MFMA12(1, 0, bf0)                                                          \
    __builtin_amdgcn_s_setprio(0);                                             \
  }

#define KTILE(RB, WB, KST, DO_STAGE)                                           \
  PHASE0(RB, WB, KST, DO_STAGE, 4)                                             \
  PHASE1(RB, WB, KST, DO_STAGE, 4)                                             \
  PHASE2(RB, WB, KST, DO_STAGE, 4)                                             \
  PHASE3(RB, WB, KST, DO_STAGE)

  STAGE_A(0, 0, 0) STAGE_B(0, 0, 0) STAGE_B(1, 0, 0) STAGE_A(1, 0, 0)

  for (int tp = 0; tp < 7; ++tp) {
    const int kb = tp * 128;
    KTILE(0, 1, kb + 64, 1)
    KTILE(1, 0, kb + 128, 1)
  }
  KTILE(0, 1, 960, 1)
  PHASE0(1, 0, 0, 0, 4)
  PHASE1(1, 0, 0, 0, 2)
  PHASE2(1, 0, 0, 0, 0)
  PHASE3(1, 0, 0, 0)
#undef KTILE
#undef PHASE0
#undef PHASE1
#undef PHASE2
#undef PHASE3
#undef MFMA12
#undef STAGE_A
#undef STAGE_B

  const int rowb = kg * 4;
#pragma unroll
  for (int ah = 0; ah < 2; ++ah)
#pragma unroll
    for (int bh = 0; bh < 2; ++bh)
#pragma unroll
      for (int ni = 0; ni < 3; ++ni) {
        const int col = n0g + bh * 96 + wn * 48 + ni * 16 + l15;
        const int cz = col & 1023;
        const float bv_ =
            (col < 1024) ? bq[cz] : ((col < 2048) ? bk[cz] : bv[cz]);
#pragma unroll
        for (int mi = 0; mi < 2; ++mi) {
          const int row = m0 + ah * 128 + wm * 32 + mi * 16 + rowb;
#pragma unroll
          for (int j = 0; j < 4; ++j)
            QKV[(size_t)(row + j) * 3072 + col] =
                (bf16)(acc[ah][bh][mi][ni][j] + bv_);
        }
      }
}

// ------- local attention, window +-2; 2 positions per wave ----------------
// Transient K-phase then V-phase (low VGPR -> 4 waves/SIMD); Q pre-scaled
// by 1/sqrt(H); bijective XCD-chunk block swizzle for K/V L2 locality.
__global__ __launch_bounds__(256, 4) void local_attn_kernel(
    const bf16* __restrict__ QKV, float* __restrict__ out) {
  const int t = threadIdx.x;
  const int lane = t & 63, wid = t >> 6;
  const int nb = (blockIdx.x & 7) * 128 + (blockIdx.x >> 3);
  const int p0 = nb * 8 + wid * 2;  // even
  const int s0 = p0 & 2047;
  const size_t hoff = (size_t)lane * 16;

  float q0f[16], q1f[16];
  {
    const bf16* qp = QKV + (size_t)p0 * 3072 + hoff;
    bf16x8 a0 = *reinterpret_cast<const bf16x8*>(qp);
    bf16x8 a1 = *reinterpret_cast<const bf16x8*>(qp + 8);
    bf16x8 b0 = *reinterpret_cast<const bf16x8*>(qp + 3072);
    bf16x8 b1 = *reinterpret_cast<const bf16x8*>(qp + 3072 + 8);
#pragma unroll
    for (int j = 0; j < 8; ++j) {
      q0f[j] = (float)a0[j] * (1.0f / 32.0f);
      q0f[8 + j] = (float)a1[j] * (1.0f / 32.0f);
      q1f[j] = (float)b0[j] * (1.0f / 32.0f);
      q1f[8 + j] = (float)b1[j] * (1.0f / 32.0f);
    }
  }

  bool val[6];
#pragma unroll
  for (int r = 0; r < 6; ++r) {
    const int sr = s0 - 2 + r;
    val[r] = (sr >= 0) && (sr < 2048);
  }

  float d0[5], d1[5];
#pragma unroll
  for (int w = 0; w < 5; ++w) { d0[w] = 0.f; d1[w] = 0.f; }
#pragma unroll
  for (int r = 0; r < 6; ++r) {
    if (!val[r]) continue;  // wave-uniform
    const bf16* kp = QKV + (size_t)(p0 - 2 + r) * 3072 + 1024 + hoff;
    bf16x8 k0 = *reinterpret_cast<const bf16x8*>(kp);
    bf16x8 k1 = *reinterpret_cast<const bf16x8*>(kp + 8);
    float kf[16];
#pragma unroll
    for (int j = 0; j < 8; ++j) { kf[j] = (float)k0[j]; kf[8 + j] = (float)k1[j]; }
    if (r < 5) {
      float a = 0.f;
#pragma unroll
      for (int j = 0; j < 16; ++j) a += q0f[j] * kf[j];
      d0[r] = a;
    }
    if (r > 0) {
      float b = 0.f;
#pragma unroll
      for (int j = 0; j < 16; ++j) b += q1f[j] * kf[j];
      d1[r - 1] = b;
    }
  }
#pragma unroll
  for (int off = 32; off >= 1; off >>= 1) {
#pragma unroll
    for (int w = 0; w < 5; ++w) {
      d0[w] += __shfl_xor(d0[w], off, 64);
      d1[w] += __shfl_xor(d1[w], off, 64);
    }
  }

  const float NEG = -__builtin_inff();
  float p0w[5], p1w[5];
  {
    float sc0[5], sc1[5];
#pragma unroll
    for (int w = 0; w < 5; ++w) {
      sc0[w] = val[w] ? d0[w] : NEG;
      sc1[w] = val[w + 1] ? d1[w] : NEG;
    }
    float m0_ = NEG, m1_ = NEG;
#pragma unroll
    for (int w = 0; w < 5; ++w) { m0_ = fmaxf(m0_, sc0[w]); m1_ = fmaxf(m1_, sc1[w]); }
    float su0 = 0.f, su1 = 0.f;
#pragma unroll
    for (int w = 0; w < 5; ++w) {
      p0w[w] = __expf(sc0[w] - m0_); su0 += p0w[w];
      p1w[w] = __expf(sc1[w] - m1_); su1 += p1w[w];
    }
    const float i0 = 1.0f / su0, i1 = 1.0f / su1;
#pragma unroll
    for (int w = 0; w < 5; ++w) { p0w[w] *= i0; p1w[w] *= i1; }
  }

  float of0[16], of1[16];
#pragma unroll
  for (int j = 0; j < 16; ++j) { of0[j] = 0.f; of1[j] = 0.f; }
#pragma unroll
  for (int r = 0; r < 6; ++r) {
    if (!val[r]) continue;
    const bf16* vp = QKV + (size_t)(p0 - 2 + r) * 3072 + 2048 + hoff;
    bf16x8 v0 = *reinterpret_cast<const bf16x8*>(vp);
    bf16x8 v1 = *reinterpret_cast<const bf16x8*>(vp + 8);
    float vf[16];
#pragma unroll
    for (int j = 0; j < 8; ++j) { vf[j] = (float)v0[j]; vf[8 + j] = (float)v1[j]; }
    if (r < 5) {
      const float pw = p0w[r];
#pragma unroll
      for (int j = 0; j < 16; ++j) of0[j] += pw * vf[j];
    }
    if (r > 0) {
      const float pw = p1w[r - 1];
#pragma unroll
      for (int j = 0; j < 16; ++j) of1[j] += pw * vf[j];
    }
  }

  float* op0 = out + (size_t)p0 * 1024 + hoff;
  float* op1 = op0 + 1024;
#pragma unroll
  for (int j4 = 0; j4 < 4; ++j4) {
    f32x4 o0 = {of0[4 * j4], of0[4 * j4 + 1], of0[4 * j4 + 2], of0[4 * j4 + 3]};
    f32x4 o1 = {of1[4 * j4], of1[4 * j4 + 1], of1[4 * j4 + 2], of1[4 * j4 + 3]};
    *reinterpret_cast<f32x4*>(op0 + 4 * j4) = o0;
    *reinterpret_cast<f32x4*>(op1 + 4 * j4) = o1;
  }
}

extern "C" void kernel_launch(void* const* d_in, const int* in_sizes, int n_in,
                              void* d_out, int out_size, void* d_ws,
                              size_t ws_size, hipStream_t stream) {
  const float* x  = (const float*)d_in[0];
  const float* Wq = (const float*)d_in[1];
  const float* bq = (const float*)d_in[2];
  const float* Wk = (const float*)d_in[3];
  const float* bk = (const float*)d_in[4];
  const float* Wv = (const float*)d_in[5];
  const float* bv = (const float*)d_in[6];

  char* ws = (char*)d_ws;
  bf16* xb  = (bf16*)ws;                       // 16 MB: x as bf16
  bf16* Wt  = (bf16*)(ws + (size_t)16777216);  // 6 MB: [3072][1024] W^T bf16
  bf16* QKV = (bf16*)(ws + (size_t)23068672);  // 48 MB: fused [8192][3072]
  float* outf = (float*)d_out;

  prep_kernel<<<dim3(32, 32, 4), 256, 0, stream>>>(x, Wq, Wk, Wv, xb, Wt);
  qkv_gemm_kernel<<<dim3(16, 32), 512, 0, stream>>>(xb, Wt, bq, bk, bv, QKV);
  local_attn_kernel<<<1024, 256, 0, stream>>>(QKV, outf);
}

// Round 21
// 93.756 us; speedup vs baseline: 3.4298x; 1.0143x over previous
//
#include <hip/hip_runtime.h>
#include <hip/hip_bf16.h>

typedef __bf16 bf16;
typedef __attribute__((ext_vector_type(4))) __bf16 bf16x4;
typedef __attribute__((ext_vector_type(8))) __bf16 bf16x8;
typedef __attribute__((ext_vector_type(4))) float f32x4;

#define GLD_LDS16(g, l)                                              \
  __builtin_amdgcn_global_load_lds(                                  \
      (const __attribute__((address_space(1))) void*)(g),            \
      (__attribute__((address_space(3))) void*)(l), 16, 0, 0)

// ---- prep: z<3 -> transpose+cast W[z] (K,N)->(N,K) bf16; z==3 -> cast x ----
__global__ void prep_kernel(const float* __restrict__ x,
                            const float* __restrict__ Wq,
                            const float* __restrict__ Wk,
                            const float* __restrict__ Wv,
                            bf16* __restrict__ xb, bf16* __restrict__ Wt) {
  __shared__ float tile[32][33];
  const int z = blockIdx.z;
  const int t = threadIdx.x;
  if (z < 3) {
    const float* W = (z == 0) ? Wq : ((z == 1) ? Wk : Wv);
    bf16* out = Wt + (size_t)z * 1024 * 1024;
    const int k0 = blockIdx.x * 32, n0 = blockIdx.y * 32;
    const int r = t >> 3, c = (t & 7) * 4;
    float4 v = *reinterpret_cast<const float4*>(&W[(size_t)(k0 + r) * 1024 + n0 + c]);
    tile[r][c + 0] = v.x; tile[r][c + 1] = v.y;
    tile[r][c + 2] = v.z; tile[r][c + 3] = v.w;
    __syncthreads();
    bf16x4 o;
    o[0] = (bf16)tile[c + 0][r]; o[1] = (bf16)tile[c + 1][r];
    o[2] = (bf16)tile[c + 2][r]; o[3] = (bf16)tile[c + 3][r];
    *reinterpret_cast<bf16x4*>(&out[(size_t)(n0 + r) * 1024 + k0 + c]) = o;
  } else {
    const int tid = (blockIdx.y * 32 + blockIdx.x) * 256 + t;
#pragma unroll
    for (int i = 0; i < 8; ++i) {
      const int idx = tid + i * 262144;
      float4 v = reinterpret_cast<const float4*>(x)[idx];
      bf16x4 o;
      o[0] = (bf16)v.x; o[1] = (bf16)v.y; o[2] = (bf16)v.z; o[3] = (bf16)v.w;
      reinterpret_cast<bf16x4*>(xb)[idx] = o;
    }
  }
}

// --------- fused QKV GEMM: C[8192][3072] = x @ Wt^T + bias ----------------
// R15 (best GEMM: 57.5 us): 8-phase, BM=256 BN=192 BK=64, grid 32x16 = 512
// = exactly 2 rounds; 8 waves 4Mx2N; 12 MFMA/phase; vmcnt(4) @P0/P1/P2,
// none @P3; tail 4/2/0. FROZEN (11 structures bracketed; this is optimal).
__global__ __launch_bounds__(512, 2) void qkv_gemm_kernel(
    const bf16* __restrict__ xb, const bf16* __restrict__ Wt,
    const float* __restrict__ bq, const float* __restrict__ bk,
    const float* __restrict__ bv, bf16* __restrict__ QKV) {
  __shared__ bf16 ldsA[2][256 * 64];  // 64 KB
  __shared__ bf16 ldsB[2][192 * 64];  // 48 KB

  const int n0g = blockIdx.x * 192;  // may cross q/k/v boundaries
  const int m0 = blockIdx.y * 256;

  const int t = threadIdx.x;
  const int lane = t & 63, wid = t >> 6;
  const int wm = wid >> 1, wn = wid & 1;
  const int l15 = lane & 15, kg = lane >> 4;

  const int trow = t >> 3;
  const int csrc = (((t & 7) * 16) ^ ((trow & 7) << 4)) >> 1;

  auto stA = [&](int h, int c, int kt, int wb) {
    GLD_LDS16(xb + (size_t)(m0 + h * 128 + c * 64 + trow) * 1024 + kt + csrc,
              &ldsA[wb][h * 8192 + c * 4096 + t * 8]);
  };
  auto stB = [&](int h, int c, int kt, int wb) {
    GLD_LDS16(Wt + (size_t)(n0g + h * 96 + c * 32 + trow) * 1024 + kt + csrc,
              &ldsB[wb][h * 6144 + c * 2048 + t * 8]);
  };
#define STAGE_A(H, KT, WB) { stA(H, 0, KT, WB); stA(H, 1, KT, WB); }
#define STAGE_B(H, KT, WB) { stB(H, 0, KT, WB); stB(H, 1, KT, WB); }

  auto readA = [&](int rb, int ah, int mi, int ks) {
    const int row = wm * 32 + mi * 16 + l15;
    const int colb = (ks * 64 + kg * 16) ^ ((l15 & 7) << 4);
    return *reinterpret_cast<const bf16x8*>(
        &ldsA[rb][ah * 8192 + row * 64 + (colb >> 1)]);
  };
  auto readB = [&](int rb, int bh, int ni, int ks) {
    const int row = wn * 48 + ni * 16 + l15;
    const int colb = (ks * 64 + kg * 16) ^ ((l15 & 7) << 4);
    return *reinterpret_cast<const bf16x8*>(
        &ldsB[rb][bh * 6144 + row * 64 + (colb >> 1)]);
  };

  f32x4 acc[2][2][2][3];
#pragma unroll
  for (int a = 0; a < 2; ++a)
#pragma unroll
    for (int b = 0; b < 2; ++b)
#pragma unroll
      for (int i = 0; i < 2; ++i)
#pragma unroll
        for (int j = 0; j < 3; ++j) {
          f32x4 zz = {0.f, 0.f, 0.f, 0.f};
          acc[a][b][i][j] = zz;
        }

  bf16x8 af[2][2], bf0[3][2], bf1[3][2];

#define MFMA12(AH, BH, BF)                                                     \
    _Pragma("unroll")                                                          \
    for (int mi = 0; mi < 2; ++mi)                                             \
      _Pragma("unroll")                                                        \
      for (int ni = 0; ni < 3; ++ni) {                                         \
        acc[AH][BH][mi][ni] = __builtin_amdgcn_mfma_f32_16x16x32_bf16(         \
            af[mi][0], BF[ni][0], acc[AH][BH][mi][ni], 0, 0, 0);               \
        acc[AH][BH][mi][ni] = __builtin_amdgcn_mfma_f32_16x16x32_bf16(         \
            af[mi][1], BF[ni][1], acc[AH][BH][mi][ni], 0, 0, 0);               \
      }

#define PHASE0(RB, WB, KST, DO_STAGE, WN)                                      \
  {                                                                            \
    asm volatile("s_waitcnt vmcnt(" #WN ")" ::: "memory");                     \
    __builtin_amdgcn_s_barrier();                                              \
    __builtin_amdgcn_sched_barrier(0);                                         \
    _Pragma("unroll")                                                          \
    for (int mi = 0; mi < 2; ++mi)                                             \
      _Pragma("unroll")                                                        \
      for (int ks = 0; ks < 2; ++ks) af[mi][ks] = readA(RB, 0, mi, ks);        \
    _Pragma("unroll")                                                          \
    for (int ni = 0; ni < 3; ++ni)                                             \
      _Pragma("unroll")                                                        \
      for (int ks = 0; ks < 2; ++ks) bf0[ni][ks] = readB(RB, 0, ni, ks);       \
    __builtin_amdgcn_sched_barrier(0);                                         \
    if (DO_STAGE) STAGE_A(0, KST, WB);                                         \
    asm volatile("s_waitcnt lgkmcnt(0)" ::: "memory");                         \
    __builtin_amdgcn_sched_barrier(0);                                         \
    __builtin_amdgcn_s_setprio(1);                                             \
    MFMA12(0, 0, bf0)                                                          \
    __builtin_amdgcn_s_setprio(0);                                             \
  }

#define PHASE1(RB, WB, KST, DO_STAGE, WN)                                      \
  {                                                                            \
    asm volatile("s_waitcnt vmcnt(" #WN ")" ::: "memory");                     \
    __builtin_amdgcn_s_barrier();                                              \
    __builtin_amdgcn_sched_barrier(0);                                         \
    _Pragma("unroll")                                                          \
    for (int ni = 0; ni < 3; ++ni)                                             \
      _Pragma("unroll")                                                        \
      for (int ks = 0; ks < 2; ++ks) bf1[ni][ks] = readB(RB, 1, ni, ks);       \
    __builtin_amdgcn_sched_barrier(0);                                         \
    if (DO_STAGE) STAGE_B(0, KST, WB);                                         \
    asm volatile("s_waitcnt lgkmcnt(0)" ::: "memory");                         \
    __builtin_amdgcn_sched_barrier(0);                                         \
    __builtin_amdgcn_s_setprio(1);                                             \
    MFMA12(0, 1, bf1)                                                          \
    __builtin_amdgcn_s_setprio(0);                                             \
  }

#define PHASE2(RB, WB, KST, DO_STAGE, WN)                                      \
  {                                                                            \
    asm volatile("s_waitcnt vmcnt(" #WN ")" ::: "memory");                     \
    __builtin_amdgcn_s_barrier();                                              \
    __builtin_amdgcn_sched_barrier(0);                                         \
    _Pragma("unroll")                                                          \
    for (int mi = 0; mi < 2; ++mi)                                             \
      _Pragma("unroll")                                                        \
      for (int ks = 0; ks < 2; ++ks) af[mi][ks] = readA(RB, 1, mi, ks);        \
    __builtin_amdgcn_sched_barrier(0);                                         \
    if (DO_STAGE) STAGE_B(1, KST, WB);                                         \
    asm volatile("s_waitcnt lgkmcnt(0)" ::: "memory");                         \
    __builtin_amdgcn_sched_barrier(0);                                         \
    __builtin_amdgcn_s_setprio(1);                                             \
    MFMA12(1, 1, bf1)                                                          \
    __builtin_amdgcn_s_setprio(0);                                             \
  }

#define PHASE3(RB, WB, KST, DO_STAGE)                                          \
  {                                                                            \
    if (DO_STAGE) STAGE_A(1, KST, WB);                                         \
    __builtin_amdgcn_s_setprio(1);                                             \
    MFMA12(1, 0, bf0)                                                          \
    __builtin_amdgcn_s_setprio(0);                                             \
  }

#define KTILE(RB, WB, KST, DO_STAGE)                                           \
  PHASE0(RB, WB, KST, DO_STAGE, 4)                                             \
  PHASE1(RB, WB, KST, DO_STAGE, 4)                                             \
  PHASE2(RB, WB, KST, DO_STAGE, 4)                                             \
  PHASE3(RB, WB, KST, DO_STAGE)

  STAGE_A(0, 0, 0) STAGE_B(0, 0, 0) STAGE_B(1, 0, 0) STAGE_A(1, 0, 0)

  for (int tp = 0; tp < 7; ++tp) {
    const int kb = tp * 128;
    KTILE(0, 1, kb + 64, 1)
    KTILE(1, 0, kb + 128, 1)
  }
  KTILE(0, 1, 960, 1)
  PHASE0(1, 0, 0, 0, 4)
  PHASE1(1, 0, 0, 0, 2)
  PHASE2(1, 0, 0, 0, 0)
  PHASE3(1, 0, 0, 0)
#undef KTILE
#undef PHASE0
#undef PHASE1
#undef PHASE2
#undef PHASE3
#undef MFMA12
#undef STAGE_A
#undef STAGE_B

  const int rowb = kg * 4;
#pragma unroll
  for (int ah = 0; ah < 2; ++ah)
#pragma unroll
    for (int bh = 0; bh < 2; ++bh)
#pragma unroll
      for (int ni = 0; ni < 3; ++ni) {
        const int col = n0g + bh * 96 + wn * 48 + ni * 16 + l15;
        const int cz = col & 1023;
        const float bv_ =
            (col < 1024) ? bq[cz] : ((col < 2048) ? bk[cz] : bv[cz]);
#pragma unroll
        for (int mi = 0; mi < 2; ++mi) {
          const int row = m0 + ah * 128 + wm * 32 + mi * 16 + rowb;
#pragma unroll
          for (int j = 0; j < 4; ++j)
            QKV[(size_t)(row + j) * 3072 + col] =
                (bf16)(acc[ah][bh][mi][ni][j] + bv_);
        }
      }
}

// ------- local attention, window +-2; 2 positions per wave ----------------
// Branch-free loads: row index clamped to batch range (clamped rows hold
// finite in-batch values; invalid contributions are zeroed exactly because
// softmax weights are exp(-inf)=0). All 6 K loads (then 6 V loads) issue
// back-to-back -> 6 outstanding per phase. Transient K/V phases keep VGPR
// ~110 -> 4 waves/SIMD. XCD-chunk swizzle for L2 locality.
__global__ __launch_bounds__(256, 4) void local_attn_kernel(
    const bf16* __restrict__ QKV, float* __restrict__ out) {
  const int t = threadIdx.x;
  const int lane = t & 63, wid = t >> 6;
  const int nb = (blockIdx.x & 7) * 128 + (blockIdx.x >> 3);
  const int p0 = nb * 8 + wid * 2;  // even
  const int s0 = p0 & 2047;
  const int base = p0 - s0;  // batch start row
  const size_t hoff = (size_t)lane * 16;

  float q0f[16], q1f[16];
  {
    const bf16* qp = QKV + (size_t)p0 * 3072 + hoff;
    bf16x8 a0 = *reinterpret_cast<const bf16x8*>(qp);
    bf16x8 a1 = *reinterpret_cast<const bf16x8*>(qp + 8);
    bf16x8 b0 = *reinterpret_cast<const bf16x8*>(qp + 3072);
    bf16x8 b1 = *reinterpret_cast<const bf16x8*>(qp + 3072 + 8);
#pragma unroll
    for (int j = 0; j < 8; ++j) {
      q0f[j] = (float)a0[j] * (1.0f / 32.0f);
      q0f[8 + j] = (float)a1[j] * (1.0f / 32.0f);
      q1f[j] = (float)b0[j] * (1.0f / 32.0f);
      q1f[8 + j] = (float)b1[j] * (1.0f / 32.0f);
    }
  }

  bool val[6];
  int rowg[6];  // clamped global row (always valid)
#pragma unroll
  for (int r = 0; r < 6; ++r) {
    const int sr = s0 - 2 + r;
    val[r] = (sr >= 0) && (sr < 2048);
    const int rc = (sr < 0) ? 0 : ((sr > 2047) ? 2047 : sr);
    rowg[r] = base + rc;
  }

  // ---- phase K: 6 unguarded loads (batched), then dots; rows transient ----
  bf16x8 kr[6][2];
#pragma unroll
  for (int r = 0; r < 6; ++r) {
    const bf16* kp = QKV + (size_t)rowg[r] * 3072 + 1024 + hoff;
    kr[r][0] = *reinterpret_cast<const bf16x8*>(kp);
    kr[r][1] = *reinterpret_cast<const bf16x8*>(kp + 8);
  }
  float d0[5], d1[5];
#pragma unroll
  for (int w = 0; w < 5; ++w) { d0[w] = 0.f; d1[w] = 0.f; }
#pragma unroll
  for (int r = 0; r < 6; ++r) {
    float kf[16];
#pragma unroll
    for (int j = 0; j < 8; ++j) {
      kf[j] = (float)kr[r][0][j];
      kf[8 + j] = (float)kr[r][1][j];
    }
    if (r < 5) {
      float a = 0.f;
#pragma unroll
      for (int j = 0; j < 16; ++j) a += q0f[j] * kf[j];
      d0[r] = a;
    }
    if (r > 0) {
      float b = 0.f;
#pragma unroll
      for (int j = 0; j < 16; ++j) b += q1f[j] * kf[j];
      d1[r - 1] = b;
    }
  }
#pragma unroll
  for (int off = 32; off >= 1; off >>= 1) {
#pragma unroll
    for (int w = 0; w < 5; ++w) {
      d0[w] += __shfl_xor(d0[w], off, 64);
      d1[w] += __shfl_xor(d1[w], off, 64);
    }
  }

  // ---- dual softmax (scores pre-scaled; invalid -> -inf -> weight 0) ----
  const float NEG = -__builtin_inff();
  float p0w[5], p1w[5];
  {
    float sc0[5], sc1[5];
#pragma unroll
    for (int w = 0; w < 5; ++w) {
      sc0[w] = val[w] ? d0[w] : NEG;
      sc1[w] = val[w + 1] ? d1[w] : NEG;
    }
    float m0_ = NEG, m1_ = NEG;
#pragma unroll
    for (int w = 0; w < 5; ++w) { m0_ = fmaxf(m0_, sc0[w]); m1_ = fmaxf(m1_, sc1[w]); }
    float su0 = 0.f, su1 = 0.f;
#pragma unroll
    for (int w = 0; w < 5; ++w) {
      p0w[w] = __expf(sc0[w] - m0_); su0 += p0w[w];
      p1w[w] = __expf(sc1[w] - m1_); su1 += p1w[w];
    }
    const float i0 = 1.0f / su0, i1 = 1.0f / su1;
#pragma unroll
    for (int w = 0; w < 5; ++w) { p0w[w] *= i0; p1w[w] *= i1; }
  }

  // ---- phase V: 6 unguarded loads (batched); weight 0 kills invalid ----
  bf16x8 vr[6][2];
#pragma unroll
  for (int r = 0; r < 6; ++r) {
    const bf16* vp = QKV + (size_t)rowg[r] * 3072 + 2048 + hoff;
    vr[r][0] = *reinterpret_cast<const bf16x8*>(vp);
    vr[r][1] = *reinterpret_cast<const bf16x8*>(vp + 8);
  }
  float of0[16], of1[16];
#pragma unroll
  for (int j = 0; j < 16; ++j) { of0[j] = 0.f; of1[j] = 0.f; }
#pragma unroll
  for (int r = 0; r < 6; ++r) {
    float vf[16];
#pragma unroll
    for (int j = 0; j < 8; ++j) {
      vf[j] = (float)vr[r][0][j];
      vf[8 + j] = (float)vr[r][1][j];
    }
    if (r < 5) {
      const float pw = p0w[r];
#pragma unroll
      for (int j = 0; j < 16; ++j) of0[j] += pw * vf[j];
    }
    if (r > 0) {
      const float pw = p1w[r - 1];
#pragma unroll
      for (int j = 0; j < 16; ++j) of1[j] += pw * vf[j];
    }
  }

  float* op0 = out + (size_t)p0 * 1024 + hoff;
  float* op1 = op0 + 1024;
#pragma unroll
  for (int j4 = 0; j4 < 4; ++j4) {
    f32x4 o0 = {of0[4 * j4], of0[4 * j4 + 1], of0[4 * j4 + 2], of0[4 * j4 + 3]};
    f32x4 o1 = {of1[4 * j4], of1[4 * j4 + 1], of1[4 * j4 + 2], of1[4 * j4 + 3]};
    *reinterpret_cast<f32x4*>(op0 + 4 * j4) = o0;
    *reinterpret_cast<f32x4*>(op1 + 4 * j4) = o1;
  }
}

extern "C" void kernel_launch(void* const* d_in, const int* in_sizes, int n_in,
                              void* d_out, int out_size, void* d_ws,
                              size_t ws_size, hipStream_t stream) {
  const float* x  = (const float*)d_in[0];
  const float* Wq = (const float*)d_in[1];
  const float* bq = (const float*)d_in[2];
  const float* Wk = (const float*)d_in[3];
  const float* bk = (const float*)d_in[4];
  const float* Wv = (const float*)d_in[5];
  const float* bv = (const float*)d_in[6];

  char* ws = (char*)d_ws;
  bf16* xb  = (bf16*)ws;                       // 16 MB: x as bf16
  bf16* Wt  = (bf16*)(ws + (size_t)16777216);  // 6 MB: [3072][1024] W^T bf16
  bf16* QKV = (bf16*)(ws + (size_t)23068672);  // 48 MB: fused [8192][3072]
  float* outf = (float*)d_out;

  prep_kernel<<<dim3(32, 32, 4), 256, 0, stream>>>(x, Wq, Wk, Wv, xb, Wt);
  qkv_gemm_kernel<<<dim3(16, 32), 512, 0, stream>>>(xb, Wt, bq, bk, bv, QKV);
  local_attn_kernel<<<1024, 256, 0, stream>>>(QKV, outf);
}

// Round 22
// 91.819 us; speedup vs baseline: 3.5022x; 1.0211x over previous
//
#include <hip/hip_runtime.h>
#include <hip/hip_bf16.h>

typedef __bf16 bf16;
typedef __attribute__((ext_vector_type(4))) __bf16 bf16x4;
typedef __attribute__((ext_vector_type(8))) __bf16 bf16x8;
typedef __attribute__((ext_vector_type(4))) float f32x4;

#define GLD_LDS16(g, l)                                              \
  __builtin_amdgcn_global_load_lds(                                  \
      (const __attribute__((address_space(1))) void*)(g),            \
      (__attribute__((address_space(3))) void*)(l), 16, 0, 0)

// ---- prep: z<3 -> transpose+cast W[z] (K,N)->(N,K) bf16; z==3 -> cast x ----
__global__ void prep_kernel(const float* __restrict__ x,
                            const float* __restrict__ Wq,
                            const float* __restrict__ Wk,
                            const float* __restrict__ Wv,
                            bf16* __restrict__ xb, bf16* __restrict__ Wt) {
  __shared__ float tile[32][33];
  const int z = blockIdx.z;
  const int t = threadIdx.x;
  if (z < 3) {
    const float* W = (z == 0) ? Wq : ((z == 1) ? Wk : Wv);
    bf16* out = Wt + (size_t)z * 1024 * 1024;
    const int k0 = blockIdx.x * 32, n0 = blockIdx.y * 32;
    const int r = t >> 3, c = (t & 7) * 4;
    float4 v = *reinterpret_cast<const float4*>(&W[(size_t)(k0 + r) * 1024 + n0 + c]);
    tile[r][c + 0] = v.x; tile[r][c + 1] = v.y;
    tile[r][c + 2] = v.z; tile[r][c + 3] = v.w;
    __syncthreads();
    bf16x4 o;
    o[0] = (bf16)tile[c + 0][r]; o[1] = (bf16)tile[c + 1][r];
    o[2] = (bf16)tile[c + 2][r]; o[3] = (bf16)tile[c + 3][r];
    *reinterpret_cast<bf16x4*>(&out[(size_t)(n0 + r) * 1024 + k0 + c]) = o;
  } else {
    const int tid = (blockIdx.y * 32 + blockIdx.x) * 256 + t;
#pragma unroll
    for (int i = 0; i < 8; ++i) {
      const int idx = tid + i * 262144;
      float4 v = reinterpret_cast<const float4*>(x)[idx];
      bf16x4 o;
      o[0] = (bf16)v.x; o[1] = (bf16)v.y; o[2] = (bf16)v.z; o[3] = (bf16)v.w;
      reinterpret_cast<bf16x4*>(xb)[idx] = o;
    }
  }
}

// --------- fused QKV GEMM: C[8192][3072] = x @ Wt^T + bias ----------------
// R15 frozen 8-phase core (BM=256 BN=192 BK=64, 8 waves 4Mx2N, 12 MFMA/ph,
// vmcnt(4) @P0/P1/P2, none @P3, tail 4/2/0) wrapped as PERSISTENT 2-M-TILE:
// grid (16,16) = 256 blocks = exactly 1 round; each block runs the K-loop
// for m0 = base and base+256. Iter-2 prologue DMAs issue BEFORE iter-1
// epilogue stores (staging flies under the store burst); epilogue bursts
// are time-staggered across the kernel.
__global__ __launch_bounds__(512, 2) void qkv_gemm_kernel(
    const bf16* __restrict__ xb, const bf16* __restrict__ Wt,
    const float* __restrict__ bq, const float* __restrict__ bk,
    const float* __restrict__ bv, bf16* __restrict__ QKV) {
  __shared__ bf16 ldsA[2][256 * 64];  // 64 KB
  __shared__ bf16 ldsB[2][192 * 64];  // 48 KB

  const int n0g = blockIdx.x * 192;  // may cross q/k/v boundaries
  int m0 = blockIdx.y * 512;         // updated per m-iteration

  const int t = threadIdx.x;
  const int lane = t & 63, wid = t >> 6;
  const int wm = wid >> 1, wn = wid & 1;
  const int l15 = lane & 15, kg = lane >> 4;

  const int trow = t >> 3;
  const int csrc = (((t & 7) * 16) ^ ((trow & 7) << 4)) >> 1;

  auto stA = [&](int h, int c, int kt, int wb) {
    GLD_LDS16(xb + (size_t)(m0 + h * 128 + c * 64 + trow) * 1024 + kt + csrc,
              &ldsA[wb][h * 8192 + c * 4096 + t * 8]);
  };
  auto stB = [&](int h, int c, int kt, int wb) {
    GLD_LDS16(Wt + (size_t)(n0g + h * 96 + c * 32 + trow) * 1024 + kt + csrc,
              &ldsB[wb][h * 6144 + c * 2048 + t * 8]);
  };
#define STAGE_A(H, KT, WB) { stA(H, 0, KT, WB); stA(H, 1, KT, WB); }
#define STAGE_B(H, KT, WB) { stB(H, 0, KT, WB); stB(H, 1, KT, WB); }

  auto readA = [&](int rb, int ah, int mi, int ks) {
    const int row = wm * 32 + mi * 16 + l15;
    const int colb = (ks * 64 + kg * 16) ^ ((l15 & 7) << 4);
    return *reinterpret_cast<const bf16x8*>(
        &ldsA[rb][ah * 8192 + row * 64 + (colb >> 1)]);
  };
  auto readB = [&](int rb, int bh, int ni, int ks) {
    const int row = wn * 48 + ni * 16 + l15;
    const int colb = (ks * 64 + kg * 16) ^ ((l15 & 7) << 4);
    return *reinterpret_cast<const bf16x8*>(
        &ldsB[rb][bh * 6144 + row * 64 + (colb >> 1)]);
  };

  f32x4 acc[2][2][2][3];
  bf16x8 af[2][2], bf0[3][2], bf1[3][2];

#define MFMA12(AH, BH, BF)                                                     \
    _Pragma("unroll")                                                          \
    for (int mi = 0; mi < 2; ++mi)                                             \
      _Pragma("unroll")                                                        \
      for (int ni = 0; ni < 3; ++ni) {                                         \
        acc[AH][BH][mi][ni] = __builtin_amdgcn_mfma_f32_16x16x32_bf16(         \
            af[mi][0], BF[ni][0], acc[AH][BH][mi][ni], 0, 0, 0);               \
        acc[AH][BH][mi][ni] = __builtin_amdgcn_mfma_f32_16x16x32_bf16(         \
            af[mi][1], BF[ni][1], acc[AH][BH][mi][ni], 0, 0, 0);               \
      }

#define PHASE0(RB, WB, KST, DO_STAGE, WN)                                      \
  {                                                                            \
    asm volatile("s_waitcnt vmcnt(" #WN ")" ::: "memory");                     \
    __builtin_amdgcn_s_barrier();                                              \
    __builtin_amdgcn_sched_barrier(0);                                         \
    _Pragma("unroll")                                                          \
    for (int mi = 0; mi < 2; ++mi)                                             \
      _Pragma("unroll")                                                        \
      for (int ks = 0; ks < 2; ++ks) af[mi][ks] = readA(RB, 0, mi, ks);        \
    _Pragma("unroll")                                                          \
    for (int ni = 0; ni < 3; ++ni)                                             \
      _Pragma("unroll")                                                        \
      for (int ks = 0; ks < 2; ++ks) bf0[ni][ks] = readB(RB, 0, ni, ks);       \
    __builtin_amdgcn_sched_barrier(0);                                         \
    if (DO_STAGE) STAGE_A(0, KST, WB);                                         \
    asm volatile("s_waitcnt lgkmcnt(0)" ::: "memory");                         \
    __builtin_amdgcn_sched_barrier(0);                                         \
    __builtin_amdgcn_s_setprio(1);                                             \
    MFMA12(0, 0, bf0)                                                          \
    __builtin_amdgcn_s_setprio(0);                                             \
  }

#define PHASE1(RB, WB, KST, DO_STAGE, WN)                                      \
  {                                                                            \
    asm volatile("s_waitcnt vmcnt(" #WN ")" ::: "memory");                     \
    __builtin_amdgcn_s_barrier();                                              \
    __builtin_amdgcn_sched_barrier(0);                                         \
    _Pragma("unroll")                                                          \
    for (int ni = 0; ni < 3; ++ni)                                             \
      _Pragma("unroll")                                                        \
      for (int ks = 0; ks < 2; ++ks) bf1[ni][ks] = readB(RB, 1, ni, ks);       \
    __builtin_amdgcn_sched_barrier(0);                                         \
    if (DO_STAGE) STAGE_B(0, KST, WB);                                         \
    asm volatile("s_waitcnt lgkmcnt(0)" ::: "memory");                         \
    __builtin_amdgcn_sched_barrier(0);                                         \
    __builtin_amdgcn_s_setprio(1);                                             \
    MFMA12(0, 1, bf1)                                                          \
    __builtin_amdgcn_s_setprio(0);                                             \
  }

#define PHASE2(RB, WB, KST, DO_STAGE, WN)                                      \
  {                                                                            \
    asm volatile("s_waitcnt vmcnt(" #WN ")" ::: "memory");                     \
    __builtin_amdgcn_s_barrier();                                              \
    __builtin_amdgcn_sched_barrier(0);                                         \
    _Pragma("unroll")                                                          \
    for (int mi = 0; mi < 2; ++mi)                                             \
      _Pragma("unroll")                                                        \
      for (int ks = 0; ks < 2; ++ks) af[mi][ks] = readA(RB, 1, mi, ks);        \
    __builtin_amdgcn_sched_barrier(0);                                         \
    if (DO_STAGE) STAGE_B(1, KST, WB);                                         \
    asm volatile("s_waitcnt lgkmcnt(0)" ::: "memory");                         \
    __builtin_amdgcn_sched_barrier(0);                                         \
    __builtin_amdgcn_s_setprio(1);                                             \
    MFMA12(1, 1, bf1)                                                          \
    __builtin_amdgcn_s_setprio(0);                                             \
  }

#define PHASE3(RB, WB, KST, DO_STAGE)                                          \
  {                                                                            \
    if (DO_STAGE) STAGE_A(1, KST, WB);                                         \
    __builtin_amdgcn_s_setprio(1);                                             \
    MFMA12(1, 0, bf0)                                                          \
    __builtin_amdgcn_s_setprio(0);                                             \
  }

#define KTILE(RB, WB, KST, DO_STAGE)                                           \
  PHASE0(RB, WB, KST, DO_STAGE, 4)                                             \
  PHASE1(RB, WB, KST, DO_STAGE, 4)                                             \
  PHASE2(RB, WB, KST, DO_STAGE, 4)                                             \
  PHASE3(RB, WB, KST, DO_STAGE)

  const int rowb = kg * 4;

  for (int mit = 0; mit < 2; ++mit) {
    m0 = blockIdx.y * 512 + mit * 256;

#pragma unroll
    for (int a = 0; a < 2; ++a)
#pragma unroll
      for (int b = 0; b < 2; ++b)
#pragma unroll
        for (int i = 0; i < 2; ++i)
#pragma unroll
          for (int j = 0; j < 3; ++j) {
            f32x4 zz = {0.f, 0.f, 0.f, 0.f};
            acc[a][b][i][j] = zz;
          }

    // prologue for this m-tile (8 DMAs outstanding; iter 2's fly under
    // iter 1's epilogue stores, which were issued just before)
    STAGE_A(0, 0, 0) STAGE_B(0, 0, 0) STAGE_B(1, 0, 0) STAGE_A(1, 0, 0)

    for (int tp = 0; tp < 7; ++tp) {
      const int kb = tp * 128;
      KTILE(0, 1, kb + 64, 1)
      KTILE(1, 0, kb + 128, 1)
    }
    KTILE(0, 1, 960, 1)
    PHASE0(1, 0, 0, 0, 4)
    PHASE1(1, 0, 0, 0, 2)
    PHASE2(1, 0, 0, 0, 0)
    PHASE3(1, 0, 0, 0)

    // epilogue: C/D layout col = lane&15, row = (lane>>4)*4 + reg [m89/m91]
#pragma unroll
    for (int ah = 0; ah < 2; ++ah)
#pragma unroll
      for (int bh = 0; bh < 2; ++bh)
#pragma unroll
        for (int ni = 0; ni < 3; ++ni) {
          const int col = n0g + bh * 96 + wn * 48 + ni * 16 + l15;
          const int cz = col & 1023;
          const float bv_ =
              (col < 1024) ? bq[cz] : ((col < 2048) ? bk[cz] : bv[cz]);
#pragma unroll
          for (int mi = 0; mi < 2; ++mi) {
            const int row = m0 + ah * 128 + wm * 32 + mi * 16 + rowb;
#pragma unroll
            for (int j = 0; j < 4; ++j)
              QKV[(size_t)(row + j) * 3072 + col] =
                  (bf16)(acc[ah][bh][mi][ni][j] + bv_);
          }
        }
  }
#undef KTILE
#undef PHASE0
#undef PHASE1
#undef PHASE2
#undef PHASE3
#undef MFMA12
#undef STAGE_A
#undef STAGE_B
}

// ------- local attention, window +-2; 2 positions per wave ----------------
// Branch-free clamped loads (R21-proven); transient K/V phases; Q pre-scaled;
// XCD-chunk swizzle. UNCHANGED from session best.
__global__ __launch_bounds__(256, 4) void local_attn_kernel(
    const bf16* __restrict__ QKV, float* __restrict__ out) {
  const int t = threadIdx.x;
  const int lane = t & 63, wid = t >> 6;
  const int nb = (blockIdx.x & 7) * 128 + (blockIdx.x >> 3);
  const int p0 = nb * 8 + wid * 2;  // even
  const int s0 = p0 & 2047;
  const int base = p0 - s0;  // batch start row
  const size_t hoff = (size_t)lane * 16;

  float q0f[16], q1f[16];
  {
    const bf16* qp = QKV + (size_t)p0 * 3072 + hoff;
    bf16x8 a0 = *reinterpret_cast<const bf16x8*>(qp);
    bf16x8 a1 = *reinterpret_cast<const bf16x8*>(qp + 8);
    bf16x8 b0 = *reinterpret_cast<const bf16x8*>(qp + 3072);
    bf16x8 b1 = *reinterpret_cast<const bf16x8*>(qp + 3072 + 8);
#pragma unroll
    for (int j = 0; j < 8; ++j) {
      q0f[j] = (float)a0[j] * (1.0f / 32.0f);
      q0f[8 + j] = (float)a1[j] * (1.0f / 32.0f);
      q1f[j] = (float)b0[j] * (1.0f / 32.0f);
      q1f[8 + j] = (float)b1[j] * (1.0f / 32.0f);
    }
  }

  bool val[6];
  int rowg[6];  // clamped global row (always valid)
#pragma unroll
  for (int r = 0; r < 6; ++r) {
    const int sr = s0 - 2 + r;
    val[r] = (sr >= 0) && (sr < 2048);
    const int rc = (sr < 0) ? 0 : ((sr > 2047) ? 2047 : sr);
    rowg[r] = base + rc;
  }

  // ---- phase K: 6 unguarded loads (batched), then dots; rows transient ----
  bf16x8 kr[6][2];
#pragma unroll
  for (int r = 0; r < 6; ++r) {
    const bf16* kp = QKV + (size_t)rowg[r] * 3072 + 1024 + hoff;
    kr[r][0] = *reinterpret_cast<const bf16x8*>(kp);
    kr[r][1] = *reinterpret_cast<const bf16x8*>(kp + 8);
  }
  float d0[5], d1[5];
#pragma unroll
  for (int w = 0; w < 5; ++w) { d0[w] = 0.f; d1[w] = 0.f; }
#pragma unroll
  for (int r = 0; r < 6; ++r) {
    float kf[16];
#pragma unroll
    for (int j = 0; j < 8; ++j) {
      kf[j] = (float)kr[r][0][j];
      kf[8 + j] = (float)kr[r][1][j];
    }
    if (r < 5) {
      float a = 0.f;
#pragma unroll
      for (int j = 0; j < 16; ++j) a += q0f[j] * kf[j];
      d0[r] = a;
    }
    if (r > 0) {
      float b = 0.f;
#pragma unroll
      for (int j = 0; j < 16; ++j) b += q1f[j] * kf[j];
      d1[r - 1] = b;
    }
  }
#pragma unroll
  for (int off = 32; off >= 1; off >>= 1) {
#pragma unroll
    for (int w = 0; w < 5; ++w) {
      d0[w] += __shfl_xor(d0[w], off, 64);
      d1[w] += __shfl_xor(d1[w], off, 64);
    }
  }

  // ---- dual softmax (scores pre-scaled; invalid -> -inf -> weight 0) ----
  const float NEG = -__builtin_inff();
  float p0w[5], p1w[5];
  {
    float sc0[5], sc1[5];
#pragma unroll
    for (int w = 0; w < 5; ++w) {
      sc0[w] = val[w] ? d0[w] : NEG;
      sc1[w] = val[w + 1] ? d1[w] : NEG;
    }
    float m0_ = NEG, m1_ = NEG;
#pragma unroll
    for (int w = 0; w < 5; ++w) { m0_ = fmaxf(m0_, sc0[w]); m1_ = fmaxf(m1_, sc1[w]); }
    float su0 = 0.f, su1 = 0.f;
#pragma unroll
    for (int w = 0; w < 5; ++w) {
      p0w[w] = __expf(sc0[w] - m0_); su0 += p0w[w];
      p1w[w] = __expf(sc1[w] - m1_); su1 += p1w[w];
    }
    const float i0 = 1.0f / su0, i1 = 1.0f / su1;
#pragma unroll
    for (int w = 0; w < 5; ++w) { p0w[w] *= i0; p1w[w] *= i1; }
  }

  // ---- phase V: 6 unguarded loads (batched); weight 0 kills invalid ----
  bf16x8 vr[6][2];
#pragma unroll
  for (int r = 0; r < 6; ++r) {
    const bf16* vp = QKV + (size_t)rowg[r] * 3072 + 2048 + hoff;
    vr[r][0] = *reinterpret_cast<const bf16x8*>(vp);
    vr[r][1] = *reinterpret_cast<const bf16x8*>(vp + 8);
  }
  float of0[16], of1[16];
#pragma unroll
  for (int j = 0; j < 16; ++j) { of0[j] = 0.f; of1[j] = 0.f; }
#pragma unroll
  for (int r = 0; r < 6; ++r) {
    float vf[16];
#pragma unroll
    for (int j = 0; j < 8; ++j) {
      vf[j] = (float)vr[r][0][j];
      vf[8 + j] = (float)vr[r][1][j];
    }
    if (r < 5) {
      const float pw = p0w[r];
#pragma unroll
      for (int j = 0; j < 16; ++j) of0[j] += pw * vf[j];
    }
    if (r > 0) {
      const float pw = p1w[r - 1];
#pragma unroll
      for (int j = 0; j < 16; ++j) of1[j] += pw * vf[j];
    }
  }

  float* op0 = out + (size_t)p0 * 1024 + hoff;
  float* op1 = op0 + 1024;
#pragma unroll
  for (int j4 = 0; j4 < 4; ++j4) {
    f32x4 o0 = {of0[4 * j4], of0[4 * j4 + 1], of0[4 * j4 + 2], of0[4 * j4 + 3]};
    f32x4 o1 = {of1[4 * j4], of1[4 * j4 + 1], of1[4 * j4 + 2], of1[4 * j4 + 3]};
    *reinterpret_cast<f32x4*>(op0 + 4 * j4) = o0;
    *reinterpret_cast<f32x4*>(op1 + 4 * j4) = o1;
  }
}

extern "C" void kernel_launch(void* const* d_in, const int* in_sizes, int n_in,
                              void* d_out, int out_size, void* d_ws,
                              size_t ws_size, hipStream_t stream) {
  const float* x  = (const float*)d_in[0];
  const float* Wq = (const float*)d_in[1];
  const float* bq = (const float*)d_in[2];
  const float* Wk = (const float*)d_in[3];
  const float* bk = (const float*)d_in[4];
  const float* Wv = (const float*)d_in[5];
  const float* bv = (const float*)d_in[6];

  char* ws = (char*)d_ws;
  bf16* xb  = (bf16*)ws;                       // 16 MB: x as bf16
  bf16* Wt  = (bf16*)(ws + (size_t)16777216);  // 6 MB: [3072][1024] W^T bf16
  bf16* QKV = (bf16*)(ws + (size_t)23068672);  // 48 MB: fused [8192][3072]
  float* outf = (float*)d_out;

  prep_kernel<<<dim3(32, 32, 4), 256, 0, stream>>>(x, Wq, Wk, Wv, xb, Wt);
  qkv_gemm_kernel<<<dim3(16, 16), 512, 0, stream>>>(xb, Wt, bq, bk, bv, QKV);
  local_attn_kernel<<<1024, 256, 0, stream>>>(QKV, outf);
}